// Round 15
// baseline (399.265 us; speedup 1.0000x reference)
//
#include <hip/hip_runtime.h>
#include <math.h>

// Problem constants (fixed by reference)
#define BN   2
#define SEQ  2048
#define DIM  1024
#define NH   16
#define DH   64
#define TAB  1024          // 2*MAX_REL
#define SCALE 0.125f       // 1/sqrt(64)
#define LOG2E 1.44269504088896340736f
#define C2PP 4096          // padded c2p entries per head (edge-replicated)

typedef __attribute__((ext_vector_type(8))) short bf16x8;
typedef __attribute__((ext_vector_type(4))) float f32x4;

#if defined(__has_builtin)
#if __has_builtin(__builtin_amdgcn_exp2f)
#define EXP2F(x) __builtin_amdgcn_exp2f(x)
#else
#define EXP2F(x) exp2f(x)
#endif
#else
#define EXP2F(x) exp2f(x)
#endif

__device__ __forceinline__ short f2b(float f) {            // RNE float->bf16
    union { float f; unsigned u; } x; x.f = f;
    return (short)((x.u + 0x7fffu + ((x.u >> 16) & 1u)) >> 16);
}
__device__ __forceinline__ float b2f(short s) {
    union { float f; unsigned u; } x; x.u = ((unsigned)(unsigned short)s) << 16;
    return x.f;
}

// async global->LDS, 16B per lane; dest must be contiguous in lane order
#define GLDS16(gp, lp) __builtin_amdgcn_global_load_lds( \
    (const __attribute__((address_space(1))) void*)(gp), \
    (__attribute__((address_space(3))) void*)(lp), 16, 0, 0)

// XOR-swizzled tile (rows of 64 shorts, 8 chunks of 8): global chunk (row,kq)
// lives at LDS chunk (row, kq ^ (row&7)). Fragment read = one b128.
__device__ __forceinline__ bf16x8 fragS(const short* base, int row, int kq) {
    return *(const bf16x8*)(base + row * 64 + ((kq ^ (row & 7)) << 3));
}

// ---------------------------------------------------------------------------
// Kernel 0: fused fp32 -> bf16 convert: hs, Wq, Wk, Wv, pos_table (one launch)
// ---------------------------------------------------------------------------
__global__ __launch_bounds__(256) void f2b_multi_kernel(
    const float* __restrict__ s0, short* __restrict__ d0, int n0,
    const float* __restrict__ s1, short* __restrict__ d1,
    const float* __restrict__ s2, short* __restrict__ d2,
    const float* __restrict__ s3, short* __restrict__ d3, int nw,
    const float* __restrict__ s4, short* __restrict__ d4, int n4)
{
    const int z = blockIdx.z;
    const float* src = z == 0 ? s0 : (z == 1 ? s1 : (z == 2 ? s2 : (z == 3 ? s3 : s4)));
    short* dst       = z == 0 ? d0 : (z == 1 ? d1 : (z == 2 ? d2 : (z == 3 ? d3 : d4)));
    const int n      = z == 0 ? n0 : (z == 4 ? n4 : nw);
    int i = (blockIdx.x * 256 + threadIdx.x) * 8;
    if (i >= n) return;
    float4 a = *(const float4*)&src[i];
    float4 b = *(const float4*)&src[i + 4];
    bf16x8 o = { f2b(a.x), f2b(a.y), f2b(a.z), f2b(a.w),
                 f2b(b.x), f2b(b.y), f2b(b.z), f2b(b.w) };
    *(bf16x8*)&dst[i] = o;
}

// ---------------------------------------------------------------------------
// Kernel 1: bf16 MFMA QKV projection, glds + swizzled tiles.
// q output is pre-scaled by 0.125*log2(e) (folds softmax scale + exp->exp2).
// ---------------------------------------------------------------------------
__global__ __launch_bounds__(256) void qkv_mfma_kernel(
    const short* __restrict__ xb,
    const short* __restrict__ Wqb, const float* __restrict__ bq,
    const short* __restrict__ Wkb, const float* __restrict__ bk,
    const short* __restrict__ Wvb, const float* __restrict__ bv,
    short* __restrict__ q, short* __restrict__ k, short* __restrict__ v)
{
    const int which = blockIdx.z;
    const short* W    = which == 0 ? Wqb : (which == 1 ? Wkb : Wvb);
    const float* bias = which == 0 ? bq  : (which == 1 ? bk  : bv);
    short* outp       = which == 0 ? q   : (which == 1 ? k   : v);
    const float osc   = which == 0 ? SCALE * LOG2E : 1.0f;

    const int m0 = blockIdx.y * 128;
    const int n0 = blockIdx.x * 128;

    __shared__ short As[128 * 64];
    __shared__ short Bs[128 * 64];

    const int t  = threadIdx.x;
    const int w  = t >> 6;
    const int q4 = (t >> 4) & 3;
    const int l  = t & 15;
    const int wm = (w >> 1) * 64;
    const int wn = (w & 1) * 64;

    f32x4 acc[4][4];
#pragma unroll
    for (int mt = 0; mt < 4; ++mt)
#pragma unroll
        for (int nt = 0; nt < 4; ++nt) acc[mt][nt] = (f32x4){0.f,0.f,0.f,0.f};

    for (int k0 = 0; k0 < DIM; k0 += 64) {
        __syncthreads();
#pragma unroll
        for (int p = 0; p < 4; ++p) {           // 128 rows x 8 chunks = 1024
            const int cq = p * 256 + t;
            const int row = cq >> 3, bd = cq & 7;
            const int goff = (bd ^ (row & 7)) << 3;
            GLDS16(xb + (size_t)(m0 + row) * DIM + k0 + goff, As + cq * 8);
            GLDS16(W  + (size_t)(n0 + row) * DIM + k0 + goff, Bs + cq * 8);
        }
        __syncthreads();
#pragma unroll
        for (int kc = 0; kc < 2; ++kc) {
            bf16x8 af[4], bf[4];
#pragma unroll
            for (int mt = 0; mt < 4; ++mt) af[mt] = fragS(As, wm + mt*16 + l, kc*4 + q4);
#pragma unroll
            for (int nt = 0; nt < 4; ++nt) bf[nt] = fragS(Bs, wn + nt*16 + l, kc*4 + q4);
#pragma unroll
            for (int mt = 0; mt < 4; ++mt)
#pragma unroll
                for (int nt = 0; nt < 4; ++nt)
                    acc[mt][nt] = __builtin_amdgcn_mfma_f32_16x16x32_bf16(
                        af[mt], bf[nt], acc[mt][nt], 0, 0, 0);
        }
    }

    float bv4[4];
#pragma unroll
    for (int nt = 0; nt < 4; ++nt) bv4[nt] = bias[n0 + wn + nt*16 + l];
#pragma unroll
    for (int mt = 0; mt < 4; ++mt) {
#pragma unroll
        for (int r = 0; r < 4; ++r) {
            const int m  = m0 + wm + mt*16 + q4*4 + r;
            const int b_ = m >> 11, s_ = m & 2047;
#pragma unroll
            for (int nt = 0; nt < 4; ++nt) {
                const int o  = n0 + wn + nt*16 + l;
                const int h_ = o >> 6, d_ = o & 63;
                outp[((size_t)(b_*NH + h_) * SEQ + s_) * DH + d_] =
                    f2b((acc[mt][nt][r] + bv4[nt]) * osc);
            }
        }
    }
}

// ---------------------------------------------------------------------------
// Kernel 2: qsum + PADDED c2p lookup table (4096/head, edge-replicated so
// attn needs no clamps). q carries 0.125*log2e -> x8 restores qsum*log2e.
// ---------------------------------------------------------------------------
__global__ __launch_bounds__(256) void qsum_c2p_kernel(
    const short* __restrict__ q, const float* __restrict__ pt, float* __restrict__ c2pP)
{
    const int bh = blockIdx.x;
    const short* qb = q + (size_t)bh * SEQ * DH;
    float* outb = c2pP + (size_t)bh * C2PP;
    __shared__ float part[32][72];
    __shared__ float qs[64];
    __shared__ float edge[2];
    const int t = threadIdx.x;
    const int dg = t & 7, sc = t >> 3;
    float a[8];
#pragma unroll
    for (int c = 0; c < 8; ++c) a[c] = 0.f;
    for (int s = sc * 64; s < sc * 64 + 64; ++s) {
        bf16x8 vv = *(const bf16x8*)&qb[(size_t)s * DH + dg * 8];
#pragma unroll
        for (int c = 0; c < 8; ++c) a[c] += b2f(vv[c]);
    }
#pragma unroll
    for (int c = 0; c < 8; ++c) part[sc][dg*8 + c] = a[c];
    __syncthreads();
    if (t < 64) {
        float s = 0.f;
#pragma unroll 8
        for (int i = 0; i < 32; ++i) s += part[i][t];
        qs[t] = s * 8.0f;           // undo the 0.125 folded into q (keeps log2e)
    }
    __syncthreads();
    for (int c = t; c < TAB; c += 256) {
        const float* ptr = pt + (size_t)c * DH;
        float s = 0.f;
#pragma unroll
        for (int dd = 0; dd < DH; dd += 4) {
            float4 p4 = *(const float4*)&ptr[dd];
            s += qs[dd]*p4.x + qs[dd+1]*p4.y + qs[dd+2]*p4.z + qs[dd+3]*p4.w;
        }
        outb[1536 + c] = s;
        if (c == 0)    edge[0] = s;
        if (c == 1023) edge[1] = s;
    }
    __syncthreads();
    const float v0 = edge[0], v1 = edge[1];
    for (int i = t; i < 1536; i += 256) {
        outb[i] = v0;                 // pad below (index < 0 clamps to 0)
        outb[2560 + i] = v1;          // pad above (index > 1023 clamps)
    }
}

// ---------------------------------------------------------------------------
// Kernel 3: T[g][j][c] = (k_j . pt[c]) * log2e  (p2c table GEMM, bf16 B stage)
// XCD swizzle: g -> XCD g/gsub (same map as attn), so attn reads the slab
// from the L2 of the XCD that tgemm wrote it on.
// ---------------------------------------------------------------------------
__global__ __launch_bounds__(256) void tgemm_kernel(
    const short* __restrict__ kglob, const short* __restrict__ ptb,
    short* __restrict__ slab, int bh0)
{
    const int G    = gridDim.z;
    const int gsub = G >> 3;                       // G in {8,16,32}
    const int fid  = (blockIdx.z * gridDim.y + blockIdx.y) * gridDim.x + blockIdx.x;
    const int g    = (fid & 7) * gsub + ((fid >> 3) % gsub);
    const int rest = fid / (8 * gsub);             // [0, 128)
    const int m0 = (rest >> 3) * 128;   // j
    const int n0 = (rest & 7) * 128;    // c

    const int bh = bh0 + g;
    const short* A = kglob + (size_t)bh * SEQ * DH;

    __shared__ short As[128 * 64];
    __shared__ short Bs[128 * 64];

    const int t  = threadIdx.x;
    const int w  = t >> 6;
    const int q4 = (t >> 4) & 3;
    const int l  = t & 15;
    const int wm = (w >> 1) * 64;
    const int wn = (w & 1) * 64;

#pragma unroll
    for (int p = 0; p < 4; ++p) {      // 128 rows x 8 chunks = 1024 chunks
        const int cq = p * 256 + t;
        const int row = cq >> 3, bd = cq & 7;
        const int go = (bd ^ (row & 7)) << 3;
        GLDS16(A   + (size_t)(m0 + row) * DH + go, As + cq * 8);
        GLDS16(ptb + (size_t)(n0 + row) * DH + go, Bs + cq * 8);
    }
    __syncthreads();

    f32x4 acc[4][4];
#pragma unroll
    for (int mt = 0; mt < 4; ++mt)
#pragma unroll
        for (int nt = 0; nt < 4; ++nt) acc[mt][nt] = (f32x4){0.f,0.f,0.f,0.f};
#pragma unroll
    for (int kc = 0; kc < 2; ++kc) {
        bf16x8 af[4], bf[4];
#pragma unroll
        for (int mt = 0; mt < 4; ++mt) af[mt] = fragS(As, wm + mt*16 + l, kc*4 + q4);
#pragma unroll
        for (int nt = 0; nt < 4; ++nt) bf[nt] = fragS(Bs, wn + nt*16 + l, kc*4 + q4);
#pragma unroll
        for (int mt = 0; mt < 4; ++mt)
#pragma unroll
            for (int nt = 0; nt < 4; ++nt)
                acc[mt][nt] = __builtin_amdgcn_mfma_f32_16x16x32_bf16(
                    af[mt], bf[nt], acc[mt][nt], 0, 0, 0);
    }

    short* outp = slab + (size_t)g * SEQ * 1024;
#pragma unroll
    for (int mt = 0; mt < 4; ++mt)
#pragma unroll
        for (int r = 0; r < 4; ++r) {
            const int m = m0 + wm + mt*16 + q4*4 + r;
#pragma unroll
            for (int nt = 0; nt < 4; ++nt)
                outp[(size_t)m * 1024 + n0 + wn + nt*16 + l] =
                    f2b(acc[mt][nt][r] * LOG2E);
        }
}

// ---------------------------------------------------------------------------
// Kernel 4: MFMA flash attention, max-free softmax, log2 domain.
// R15 = R12 (S^T, P-in-registers, de-staged bias, single-buffer, 2 barriers
// — R11/R13/R14 proved pipelining variants regress) with:
//  * padded c2p (C2PP entries/head): C-init has NO clamps, indices
//    2048 + i - j - jl are always in [1, 4095].
//  * __launch_bounds__(256, 5): kernel needs ~60 VGPR << 96 cap; LDS
//    5 x 16.4KB = 82KB -> 5 blocks/CU (R12 measured only 35% occupancy
//    at 3 blocks; the 37us non-VALU stall pool needs TLP).
// ---------------------------------------------------------------------------
__global__ __launch_bounds__(256, 5) void attn_kernel(
    const short* __restrict__ q, const short* __restrict__ k, const short* __restrict__ v,
    const float* __restrict__ c2pP, const short* __restrict__ slab,
    short* __restrict__ ao, int bh0)
{
    const int G    = gridDim.y;
    const int gsub = G >> 3;
    const int fid  = blockIdx.y * gridDim.x + blockIdx.x;
    const int g    = (fid & 7) * gsub + ((fid >> 3) % gsub);
    const int i0   = (fid / (8 * gsub)) * 64;

    const int bh = bh0 + g;
    const int b_ = bh >> 4, h_ = bh & 15;
    const short* qbh = q + (size_t)bh * SEQ * DH;
    const short* kbh = k + (size_t)bh * SEQ * DH;
    const short* vbh = v + (size_t)bh * SEQ * DH;
    const float* c2pb = c2pP + (size_t)bh * C2PP;
    const short* Tb   = slab + (size_t)g * SEQ * 1024;

    __shared__ short Ks[64 * 64];     // swizzled [j][d]; stages Q in prologue
    __shared__ short Vt[64 * 64];     // swizzled [d][j]

    const int t    = threadIdx.x;
    const int w    = t >> 6;
    const int q4   = (t >> 4) & 3;
    const int l    = t & 15;
    const int iLoc = w*16 + l;                      // this thread's softmax row
    const int pq   = ((q4 & 1) << 1) | (q4 >> 1);   // V granule perm [0,2,1,3]

    const int jp  = t & 31;        // V stage: j pair
    const int dgv = t >> 5;        // V stage: d group

    // ---- Q prologue (staged via Ks, then freed) ----
#pragma unroll
    for (int p = 0; p < 2; ++p) {
        const int cq = p * 256 + t;
        const int row = cq >> 3, bd = cq & 7;
        GLDS16(qbh + (size_t)(i0 + row) * DH + ((bd ^ (row & 7)) << 3), Ks + cq * 8);
    }
    __syncthreads();
    const bf16x8 aq0 = fragS(Ks, w*16 + l, q4);
    const bf16x8 aq1 = fragS(Ks, w*16 + l, 4 + q4);
    __syncthreads();   // all waves done reading Q before tile-0 K overwrites Ks

    float lsum = 0.f;
    f32x4 O[4];
#pragma unroll
    for (int dt = 0; dt < 4; ++dt) O[dt] = (f32x4){0.f, 0.f, 0.f, 0.f};

    for (int j0 = 0; j0 < SEQ; j0 += 64) {
        const int Kc0 = 2559 - i0 - j0;

        // ---- K stage (glds swizzled) ----
#pragma unroll
        for (int p = 0; p < 2; ++p) {
            const int cq = p * 256 + t;
            const int row = cq >> 3, bd = cq & 7;
            GLDS16(kbh + (size_t)(j0 + row) * DH + ((bd ^ (row & 7)) << 3), Ks + cq * 8);
        }
        // ---- V transpose (b32 pair writes into swizzled [d][j]) ----
        {
            const int j = 2 * jp, d0 = dgv * 8;
            bf16x8 va = *(const bf16x8*)(vbh + (size_t)(j0 + j)     * DH + d0);
            bf16x8 vb = *(const bf16x8*)(vbh + (size_t)(j0 + j + 1) * DH + d0);
#pragma unroll
            for (int c = 0; c < 8; ++c) {
                const int d = d0 + c;
                const int slot = d * 64 + (((j >> 3) ^ (d & 7)) << 3) + (j & 7);
                short2 pr; pr.x = va[c]; pr.y = vb[c];
                *(short2*)&Vt[slot] = pr;
            }
        }
        __syncthreads();

        // ---- C-init from padded c2p (no clamps; idx in [1,4095]) ----
        f32x4 st4[4];
        const int cbB = 2048 + i0 + iLoc - j0;      // idx = cbB - jl
#pragma unroll
        for (int jt = 0; jt < 4; ++jt) {
            const int base = cbB - jt*16 - q4*4;
            st4[jt][0] = c2pb[base];
            st4[jt][1] = c2pb[base - 1];
            st4[jt][2] = c2pb[base - 2];
            st4[jt][3] = c2pb[base - 3];
        }

        // ---- band prefetch direct from T-slab (XCD L2), clamped y ----
        short tband[16];
#pragma unroll
        for (int jt = 0; jt < 4; ++jt)
#pragma unroll
            for (int r = 0; r < 4; ++r) {
                const int jl = jt*16 + q4*4 + r;
                const int y  = min(max(Kc0 - jl - iLoc, 0), TAB - 1);
                tband[jt*4 + r] = Tb[(size_t)(j0 + jl) * 1024 + y];
            }

        // ---- swapped QK^T: mfma(K_frag, Q_frag) -> S^T ----
        __builtin_amdgcn_s_setprio(1);
#pragma unroll
        for (int jt = 0; jt < 4; ++jt) {
            bf16x8 a0 = fragS(Ks, jt*16 + l, q4);
            bf16x8 a1 = fragS(Ks, jt*16 + l, 4 + q4);
            st4[jt] = __builtin_amdgcn_mfma_f32_16x16x32_bf16(a0, aq0, st4[jt], 0, 0, 0);
            st4[jt] = __builtin_amdgcn_mfma_f32_16x16x32_bf16(a1, aq1, st4[jt], 0, 0, 0);
        }
        __builtin_amdgcn_s_setprio(0);

        // ---- exp2 (uniform path; bias from registers) ----
        float pv4[4][4];
#pragma unroll
        for (int jt = 0; jt < 4; ++jt)
#pragma unroll
            for (int r = 0; r < 4; ++r) {
                pv4[jt][r] = EXP2F(st4[jt][r] + b2f(tband[jt*4 + r]));
                lsum += pv4[jt][r];
            }

        // ---- pack + permlane16_swap: PV A-frags in registers ----
        unsigned P2[4][2];
#pragma unroll
        for (int t2 = 0; t2 < 4; ++t2) {
            asm("v_cvt_pk_bf16_f32 %0, %1, %2"
                : "=v"(P2[t2][0]) : "v"(pv4[t2][0]), "v"(pv4[t2][1]));
            asm("v_cvt_pk_bf16_f32 %0, %1, %2"
                : "=v"(P2[t2][1]) : "v"(pv4[t2][2]), "v"(pv4[t2][3]));
        }
#pragma unroll
        for (int m = 0; m < 2; ++m) {
            asm("v_permlane16_swap_b32 %0, %1" : "+v"(P2[0][m]), "+v"(P2[1][m]));
            asm("v_permlane16_swap_b32 %0, %1" : "+v"(P2[2][m]), "+v"(P2[3][m]));
        }
        union { unsigned u[4]; bf16x8 v8; } UA, UB;
        UA.u[0] = P2[0][0]; UA.u[1] = P2[0][1]; UA.u[2] = P2[1][0]; UA.u[3] = P2[1][1];
        UB.u[0] = P2[2][0]; UB.u[1] = P2[2][1]; UB.u[2] = P2[3][0]; UB.u[3] = P2[3][1];

        // ---- PV (A = in-register P frags, B = V frags with granule perm) ----
        __builtin_amdgcn_s_setprio(1);
#pragma unroll
        for (int dt = 0; dt < 4; ++dt) {
            bf16x8 b0 = fragS(Vt, dt*16 + l, pq);
            bf16x8 b1 = fragS(Vt, dt*16 + l, 4 + pq);
            O[dt] = __builtin_amdgcn_mfma_f32_16x16x32_bf16(UA.v8, b0, O[dt], 0, 0, 0);
            O[dt] = __builtin_amdgcn_mfma_f32_16x16x32_bf16(UB.v8, b1, O[dt], 0, 0, 0);
        }
        __builtin_amdgcn_s_setprio(0);
        __syncthreads();   // compute done before next stage overwrites Ks/Vt
    }

    // ---- final row-sum: reduce q4-groups, then pick per-output-row ----
    lsum += __shfl_xor(lsum, 16);
    lsum += __shfl_xor(lsum, 32);

    // ---- epilogue: normalize, write ao bf16 as [b][s][h][d] ----
#pragma unroll
    for (int r = 0; r < 4; ++r) {
        const float inv = 1.f / __shfl(lsum, q4*4 + r);
        const int i_g = i0 + w*16 + q4*4 + r;
        short* dst = ao + (((size_t)b_ * SEQ + i_g) * NH + h_) * DH + l;
#pragma unroll
        for (int dt = 0; dt < 4; ++dt)
            dst[dt*16] = f2b(O[dt][r] * inv);
    }
}

// ---------------------------------------------------------------------------
// Kernel 5: output projection out = ao @ Wc.T (A bf16 glds, B fp32->bf16)
// ---------------------------------------------------------------------------
__global__ __launch_bounds__(256) void out_mfma_kernel(
    const short* __restrict__ xb, const float* __restrict__ W, float* __restrict__ out)
{
    const int m0 = blockIdx.y * 128;
    const int n0 = blockIdx.x * 128;

    __shared__ short As[128 * 64];
    __shared__ short Bs[128 * 64];

    const int t  = threadIdx.x;
    const int w  = t >> 6;
    const int q4 = (t >> 4) & 3;
    const int l  = t & 15;
    const int wm = (w >> 1) * 64;
    const int wn = (w & 1) * 64;

    f32x4 acc[4][4];
#pragma unroll
    for (int mt = 0; mt < 4; ++mt)
#pragma unroll
        for (int nt = 0; nt < 4; ++nt) acc[mt][nt] = (f32x4){0.f,0.f,0.f,0.f};

    for (int k0 = 0; k0 < DIM; k0 += 64) {
        __syncthreads();
#pragma unroll
        for (int p = 0; p < 4; ++p) {
            const int cq = p * 256 + t;
            const int row = cq >> 3, bd = cq & 7;
            GLDS16(xb + (size_t)(m0 + row) * DIM + k0 + ((bd ^ (row & 7)) << 3), As + cq * 8);
        }
        {
            const int row = t >> 1, h = t & 1;
#pragma unroll
            for (int c = 0; c < 4; ++c) {
                const int gch = h * 4 + c;
                const float* src = W + (size_t)(n0 + row) * DIM + k0 + gch * 8;
                float4 f0 = *(const float4*)src;
                float4 f1 = *(const float4*)(src + 4);
                bf16x8 o = { f2b(f0.x), f2b(f0.y), f2b(f0.z), f2b(f0.w),
                             f2b(f1.x), f2b(f1.y), f2b(f1.z), f2b(f1.w) };
                *(bf16x8*)&Bs[row * 64 + ((gch ^ (row & 7)) << 3)] = o;
            }
        }
        __syncthreads();
#pragma unroll
        for (int kc = 0; kc < 2; ++kc) {
            bf16x8 af[4], bf[4];
#pragma unroll
            for (int mt = 0; mt < 4; ++mt) af[mt] = fragS(As, wm + mt*16 + l, kc*4 + q4);
#pragma unroll
            for (int nt = 0; nt < 4; ++nt) bf[nt] = fragS(Bs, wn + nt*16 + l, kc*4 + q4);
#pragma unroll
            for (int mt = 0; mt < 4; ++mt)
#pragma unroll
                for (int nt = 0; nt < 4; ++nt)
                    acc[mt][nt] = __builtin_amdgcn_mfma_f32_16x16x32_bf16(
                        af[mt], bf[nt], acc[mt][nt], 0, 0, 0);
        }
    }
#pragma unroll
    for (int mt = 0; mt < 4; ++mt)
#pragma unroll
        for (int r = 0; r < 4; ++r) {
            const int m = m0 + wm + mt*16 + q4*4 + r;
#pragma unroll
            for (int nt = 0; nt < 4; ++nt)
                out[(size_t)m * DIM + n0 + wn + nt*16 + l] = acc[mt][nt][r];
        }
}

// ---------------------------------------------------------------------------
extern "C" void kernel_launch(void* const* d_in, const int* in_sizes, int n_in,
                              void* d_out, int out_size, void* d_ws, size_t ws_size,
                              hipStream_t stream)
{
    const float* hs = (const float*)d_in[0];
    const float* Wq = (const float*)d_in[1];
    const float* bq = (const float*)d_in[2];
    const float* Wk = (const float*)d_in[3];
    const float* bk = (const float*)d_in[4];
    const float* Wv = (const float*)d_in[5];
    const float* bv = (const float*)d_in[6];
    const float* Wc = (const float*)d_in[7];
    const float* pt = (const float*)d_in[8];
    float* out = (float*)d_out;

    // workspace (shorts): [qb][kb][vb][aob][c2pP fp32 padded][ptb bf16][slab]
    // phase-1 overlay inside slab region: xb + Wq/Wk/Wv bf16.
    const size_t XE    = (size_t)BN * SEQ * DIM;     // 4,194,304
    const size_t WE    = (size_t)DIM * DIM;          // 1,048,576
    const size_t PE    = (size_t)TAB * DH;           // 65,536
    const size_t CPSH  = (size_t)BN * NH * C2PP * 2; // padded c2p in shorts
    const size_t SLAB1 = (size_t)SEQ * 1024;         // shorts per bh

    short* sw   = (short*)d_ws;
    short* qb   = sw;
    short* kb   = sw + XE;
    short* vb   = sw + 2 * XE;
    short* aob  = sw + 3 * XE;
    float* c2pP = (float*)(sw + 4 * XE);             // BN*NH*C2PP fp32
    short* ptb  = sw + 4 * XE + CPSH;                // pos_table bf16
    short* slab = sw + 4 * XE + CPSH + PE;
    short* xb   = slab;                  // overlay (phase 1 only)
    short* wqb  = slab + XE;
    short* wkb  = wqb + WE;
    short* wvb  = wkb + WE;

    const size_t fixed_sh = 4 * XE + CPSH + PE;
    const size_t avail_sh = (ws_size / 2 > fixed_sh) ? ws_size / 2 - fixed_sh : 0;
    const int G = (avail_sh >= 32 * SLAB1) ? 32 : ((avail_sh >= 16 * SLAB1) ? 16 : 8);

    f2b_multi_kernel<<<dim3((int)(XE/2048), 1, 5), 256, 0, stream>>>(
        hs, xb, (int)XE, Wq, wqb, Wk, wkb, Wv, wvb, (int)WE, pt, ptb, (int)PE);

    qkv_mfma_kernel<<<dim3(DIM/128, (BN*SEQ)/128, 3), 256, 0, stream>>>(
        xb, wqb, bq, wkb, bk, wvb, bv, qb, kb, vb);

    qsum_c2p_kernel<<<dim3(BN*NH), 256, 0, stream>>>(qb, pt, c2pP);

    for (int bh0 = 0; bh0 < BN*NH; bh0 += G) {
        tgemm_kernel<<<dim3(1024/128, SEQ/128, G), 256, 0, stream>>>(kb, ptb, slab, bh0);
        attn_kernel<<<dim3(SEQ/64, G), 256, 0, stream>>>(qb, kb, vb, c2pP, slab, aob, bh0);
    }

    out_mfma_kernel<<<dim3(DIM/128, (BN*SEQ)/128), 256, 0, stream>>>(aob, Wc, out);
}

// Round 16
// 304.652 us; speedup vs baseline: 1.3106x; 1.3106x over previous
//
#include <hip/hip_runtime.h>
#include <math.h>

// Problem constants (fixed by reference)
#define BN   2
#define SEQ  2048
#define DIM  1024
#define NH   16
#define DH   64
#define TAB  1024          // 2*MAX_REL
#define SCALE 0.125f       // 1/sqrt(64)
#define LOG2E 1.44269504088896340736f
#define C2PP 4096          // padded c2p entries per head (edge-replicated)

typedef __attribute__((ext_vector_type(8))) short bf16x8;
typedef __attribute__((ext_vector_type(4))) float f32x4;

#if defined(__has_builtin)
#if __has_builtin(__builtin_amdgcn_exp2f)
#define EXP2F(x) __builtin_amdgcn_exp2f(x)
#else
#define EXP2F(x) exp2f(x)
#endif
#else
#define EXP2F(x) exp2f(x)
#endif

__device__ __forceinline__ short f2b(float f) {            // RNE float->bf16
    union { float f; unsigned u; } x; x.f = f;
    return (short)((x.u + 0x7fffu + ((x.u >> 16) & 1u)) >> 16);
}
__device__ __forceinline__ float b2f(short s) {
    union { float f; unsigned u; } x; x.u = ((unsigned)(unsigned short)s) << 16;
    return x.f;
}

// async global->LDS, 16B per lane; dest must be contiguous in lane order
#define GLDS16(gp, lp) __builtin_amdgcn_global_load_lds( \
    (const __attribute__((address_space(1))) void*)(gp), \
    (__attribute__((address_space(3))) void*)(lp), 16, 0, 0)

// XOR-swizzled tile (rows of 64 shorts, 8 chunks of 8): global chunk (row,kq)
// lives at LDS chunk (row, kq ^ (row&7)). Fragment read = one b128.
__device__ __forceinline__ bf16x8 fragS(const short* base, int row, int kq) {
    return *(const bf16x8*)(base + row * 64 + ((kq ^ (row & 7)) << 3));
}

// ---------------------------------------------------------------------------
// Kernel 0: fused fp32 -> bf16 convert: hs, Wq, Wk, Wv, pos_table (one launch)
// ---------------------------------------------------------------------------
__global__ __launch_bounds__(256) void f2b_multi_kernel(
    const float* __restrict__ s0, short* __restrict__ d0, int n0,
    const float* __restrict__ s1, short* __restrict__ d1,
    const float* __restrict__ s2, short* __restrict__ d2,
    const float* __restrict__ s3, short* __restrict__ d3, int nw,
    const float* __restrict__ s4, short* __restrict__ d4, int n4)
{
    const int z = blockIdx.z;
    const float* src = z == 0 ? s0 : (z == 1 ? s1 : (z == 2 ? s2 : (z == 3 ? s3 : s4)));
    short* dst       = z == 0 ? d0 : (z == 1 ? d1 : (z == 2 ? d2 : (z == 3 ? d3 : d4)));
    const int n      = z == 0 ? n0 : (z == 4 ? n4 : nw);
    int i = (blockIdx.x * 256 + threadIdx.x) * 8;
    if (i >= n) return;
    float4 a = *(const float4*)&src[i];
    float4 b = *(const float4*)&src[i + 4];
    bf16x8 o = { f2b(a.x), f2b(a.y), f2b(a.z), f2b(a.w),
                 f2b(b.x), f2b(b.y), f2b(b.z), f2b(b.w) };
    *(bf16x8*)&dst[i] = o;
}

// ---------------------------------------------------------------------------
// Kernel 1: bf16 MFMA QKV projection, glds + swizzled tiles.
// q output is pre-scaled by 0.125*log2(e) (folds softmax scale + exp->exp2).
// ---------------------------------------------------------------------------
__global__ __launch_bounds__(256) void qkv_mfma_kernel(
    const short* __restrict__ xb,
    const short* __restrict__ Wqb, const float* __restrict__ bq,
    const short* __restrict__ Wkb, const float* __restrict__ bk,
    const short* __restrict__ Wvb, const float* __restrict__ bv,
    short* __restrict__ q, short* __restrict__ k, short* __restrict__ v)
{
    const int which = blockIdx.z;
    const short* W    = which == 0 ? Wqb : (which == 1 ? Wkb : Wvb);
    const float* bias = which == 0 ? bq  : (which == 1 ? bk  : bv);
    short* outp       = which == 0 ? q   : (which == 1 ? k   : v);
    const float osc   = which == 0 ? SCALE * LOG2E : 1.0f;

    const int m0 = blockIdx.y * 128;
    const int n0 = blockIdx.x * 128;

    __shared__ short As[128 * 64];
    __shared__ short Bs[128 * 64];

    const int t  = threadIdx.x;
    const int w  = t >> 6;
    const int q4 = (t >> 4) & 3;
    const int l  = t & 15;
    const int wm = (w >> 1) * 64;
    const int wn = (w & 1) * 64;

    f32x4 acc[4][4];
#pragma unroll
    for (int mt = 0; mt < 4; ++mt)
#pragma unroll
        for (int nt = 0; nt < 4; ++nt) acc[mt][nt] = (f32x4){0.f,0.f,0.f,0.f};

    for (int k0 = 0; k0 < DIM; k0 += 64) {
        __syncthreads();
#pragma unroll
        for (int p = 0; p < 4; ++p) {           // 128 rows x 8 chunks = 1024
            const int cq = p * 256 + t;
            const int row = cq >> 3, bd = cq & 7;
            const int goff = (bd ^ (row & 7)) << 3;
            GLDS16(xb + (size_t)(m0 + row) * DIM + k0 + goff, As + cq * 8);
            GLDS16(W  + (size_t)(n0 + row) * DIM + k0 + goff, Bs + cq * 8);
        }
        __syncthreads();
#pragma unroll
        for (int kc = 0; kc < 2; ++kc) {
            bf16x8 af[4], bf[4];
#pragma unroll
            for (int mt = 0; mt < 4; ++mt) af[mt] = fragS(As, wm + mt*16 + l, kc*4 + q4);
#pragma unroll
            for (int nt = 0; nt < 4; ++nt) bf[nt] = fragS(Bs, wn + nt*16 + l, kc*4 + q4);
#pragma unroll
            for (int mt = 0; mt < 4; ++mt)
#pragma unroll
                for (int nt = 0; nt < 4; ++nt)
                    acc[mt][nt] = __builtin_amdgcn_mfma_f32_16x16x32_bf16(
                        af[mt], bf[nt], acc[mt][nt], 0, 0, 0);
        }
    }

    float bv4[4];
#pragma unroll
    for (int nt = 0; nt < 4; ++nt) bv4[nt] = bias[n0 + wn + nt*16 + l];
#pragma unroll
    for (int mt = 0; mt < 4; ++mt) {
#pragma unroll
        for (int r = 0; r < 4; ++r) {
            const int m  = m0 + wm + mt*16 + q4*4 + r;
            const int b_ = m >> 11, s_ = m & 2047;
#pragma unroll
            for (int nt = 0; nt < 4; ++nt) {
                const int o  = n0 + wn + nt*16 + l;
                const int h_ = o >> 6, d_ = o & 63;
                outp[((size_t)(b_*NH + h_) * SEQ + s_) * DH + d_] =
                    f2b((acc[mt][nt][r] + bv4[nt]) * osc);
            }
        }
    }
}

// ---------------------------------------------------------------------------
// Kernel 2: qsum + PADDED c2p lookup table (4096/head, edge-replicated so
// attn needs no clamps). q carries 0.125*log2e -> x8 restores qsum*log2e.
// ---------------------------------------------------------------------------
__global__ __launch_bounds__(256) void qsum_c2p_kernel(
    const short* __restrict__ q, const float* __restrict__ pt, float* __restrict__ c2pP)
{
    const int bh = blockIdx.x;
    const short* qb = q + (size_t)bh * SEQ * DH;
    float* outb = c2pP + (size_t)bh * C2PP;
    __shared__ float part[32][72];
    __shared__ float qs[64];
    __shared__ float edge[2];
    const int t = threadIdx.x;
    const int dg = t & 7, sc = t >> 3;
    float a[8];
#pragma unroll
    for (int c = 0; c < 8; ++c) a[c] = 0.f;
    for (int s = sc * 64; s < sc * 64 + 64; ++s) {
        bf16x8 vv = *(const bf16x8*)&qb[(size_t)s * DH + dg * 8];
#pragma unroll
        for (int c = 0; c < 8; ++c) a[c] += b2f(vv[c]);
    }
#pragma unroll
    for (int c = 0; c < 8; ++c) part[sc][dg*8 + c] = a[c];
    __syncthreads();
    if (t < 64) {
        float s = 0.f;
#pragma unroll 8
        for (int i = 0; i < 32; ++i) s += part[i][t];
        qs[t] = s * 8.0f;           // undo the 0.125 folded into q (keeps log2e)
    }
    __syncthreads();
    for (int c = t; c < TAB; c += 256) {
        const float* ptr = pt + (size_t)c * DH;
        float s = 0.f;
#pragma unroll
        for (int dd = 0; dd < DH; dd += 4) {
            float4 p4 = *(const float4*)&ptr[dd];
            s += qs[dd]*p4.x + qs[dd+1]*p4.y + qs[dd+2]*p4.z + qs[dd+3]*p4.w;
        }
        outb[1536 + c] = s;
        if (c == 0)    edge[0] = s;
        if (c == 1023) edge[1] = s;
    }
    __syncthreads();
    const float v0 = edge[0], v1 = edge[1];
    for (int i = t; i < 1536; i += 256) {
        outb[i] = v0;                 // pad below (index < 0 clamps to 0)
        outb[2560 + i] = v1;          // pad above (index > 1023 clamps)
    }
}

// ---------------------------------------------------------------------------
// Kernel 3: T[g][j][c] = (k_j . pt[c]) * log2e  (p2c table GEMM, bf16 B stage)
// XCD swizzle: g -> XCD g/gsub (same map as attn), so attn reads the slab
// from the L2 of the XCD that tgemm wrote it on.
// ---------------------------------------------------------------------------
__global__ __launch_bounds__(256) void tgemm_kernel(
    const short* __restrict__ kglob, const short* __restrict__ ptb,
    short* __restrict__ slab, int bh0)
{
    const int G    = gridDim.z;
    const int gsub = G >> 3;                       // G in {8,16,32}
    const int fid  = (blockIdx.z * gridDim.y + blockIdx.y) * gridDim.x + blockIdx.x;
    const int g    = (fid & 7) * gsub + ((fid >> 3) % gsub);
    const int rest = fid / (8 * gsub);             // [0, 128)
    const int m0 = (rest >> 3) * 128;   // j
    const int n0 = (rest & 7) * 128;    // c

    const int bh = bh0 + g;
    const short* A = kglob + (size_t)bh * SEQ * DH;

    __shared__ short As[128 * 64];
    __shared__ short Bs[128 * 64];

    const int t  = threadIdx.x;
    const int w  = t >> 6;
    const int q4 = (t >> 4) & 3;
    const int l  = t & 15;
    const int wm = (w >> 1) * 64;
    const int wn = (w & 1) * 64;

#pragma unroll
    for (int p = 0; p < 4; ++p) {      // 128 rows x 8 chunks = 1024 chunks
        const int cq = p * 256 + t;
        const int row = cq >> 3, bd = cq & 7;
        const int go = (bd ^ (row & 7)) << 3;
        GLDS16(A   + (size_t)(m0 + row) * DH + go, As + cq * 8);
        GLDS16(ptb + (size_t)(n0 + row) * DH + go, Bs + cq * 8);
    }
    __syncthreads();

    f32x4 acc[4][4];
#pragma unroll
    for (int mt = 0; mt < 4; ++mt)
#pragma unroll
        for (int nt = 0; nt < 4; ++nt) acc[mt][nt] = (f32x4){0.f,0.f,0.f,0.f};
#pragma unroll
    for (int kc = 0; kc < 2; ++kc) {
        bf16x8 af[4], bf[4];
#pragma unroll
        for (int mt = 0; mt < 4; ++mt) af[mt] = fragS(As, wm + mt*16 + l, kc*4 + q4);
#pragma unroll
        for (int nt = 0; nt < 4; ++nt) bf[nt] = fragS(Bs, wn + nt*16 + l, kc*4 + q4);
#pragma unroll
        for (int mt = 0; mt < 4; ++mt)
#pragma unroll
            for (int nt = 0; nt < 4; ++nt)
                acc[mt][nt] = __builtin_amdgcn_mfma_f32_16x16x32_bf16(
                    af[mt], bf[nt], acc[mt][nt], 0, 0, 0);
    }

    short* outp = slab + (size_t)g * SEQ * 1024;
#pragma unroll
    for (int mt = 0; mt < 4; ++mt)
#pragma unroll
        for (int r = 0; r < 4; ++r) {
            const int m = m0 + wm + mt*16 + q4*4 + r;
#pragma unroll
            for (int nt = 0; nt < 4; ++nt)
                outp[(size_t)m * 1024 + n0 + wn + nt*16 + l] =
                    f2b(acc[mt][nt][r] * LOG2E);
        }
}

// ---------------------------------------------------------------------------
// Kernel 4: MFMA flash attention, max-free softmax, log2 domain.
// R16 = R12 (S^T, P-in-registers, de-staged bias, single-buffer, 2 barriers)
// + padded clamp-free c2p C-init. __launch_bounds__(256,3): R15 proved
// (256,5) squeezes to 48 VGPR and spills catastrophically (WRITE 8->146MB);
// this kernel family needs the (256,3) budget. Occupancy-raising is CLOSED.
// ---------------------------------------------------------------------------
__global__ __launch_bounds__(256, 3) void attn_kernel(
    const short* __restrict__ q, const short* __restrict__ k, const short* __restrict__ v,
    const float* __restrict__ c2pP, const short* __restrict__ slab,
    short* __restrict__ ao, int bh0)
{
    const int G    = gridDim.y;
    const int gsub = G >> 3;
    const int fid  = blockIdx.y * gridDim.x + blockIdx.x;
    const int g    = (fid & 7) * gsub + ((fid >> 3) % gsub);
    const int i0   = (fid / (8 * gsub)) * 64;

    const int bh = bh0 + g;
    const int b_ = bh >> 4, h_ = bh & 15;
    const short* qbh = q + (size_t)bh * SEQ * DH;
    const short* kbh = k + (size_t)bh * SEQ * DH;
    const short* vbh = v + (size_t)bh * SEQ * DH;
    const float* c2pb = c2pP + (size_t)bh * C2PP;
    const short* Tb   = slab + (size_t)g * SEQ * 1024;

    __shared__ short Ks[64 * 64];     // swizzled [j][d]; stages Q in prologue
    __shared__ short Vt[64 * 64];     // swizzled [d][j]

    const int t    = threadIdx.x;
    const int w    = t >> 6;
    const int q4   = (t >> 4) & 3;
    const int l    = t & 15;
    const int iLoc = w*16 + l;                      // this thread's softmax row
    const int pq   = ((q4 & 1) << 1) | (q4 >> 1);   // V granule perm [0,2,1,3]

    const int jp  = t & 31;        // V stage: j pair
    const int dgv = t >> 5;        // V stage: d group

    // ---- Q prologue (staged via Ks, then freed) ----
#pragma unroll
    for (int p = 0; p < 2; ++p) {
        const int cq = p * 256 + t;
        const int row = cq >> 3, bd = cq & 7;
        GLDS16(qbh + (size_t)(i0 + row) * DH + ((bd ^ (row & 7)) << 3), Ks + cq * 8);
    }
    __syncthreads();
    const bf16x8 aq0 = fragS(Ks, w*16 + l, q4);
    const bf16x8 aq1 = fragS(Ks, w*16 + l, 4 + q4);
    __syncthreads();   // all waves done reading Q before tile-0 K overwrites Ks

    float lsum = 0.f;
    f32x4 O[4];
#pragma unroll
    for (int dt = 0; dt < 4; ++dt) O[dt] = (f32x4){0.f, 0.f, 0.f, 0.f};

    for (int j0 = 0; j0 < SEQ; j0 += 64) {
        const int Kc0 = 2559 - i0 - j0;

        // ---- K stage (glds swizzled) ----
#pragma unroll
        for (int p = 0; p < 2; ++p) {
            const int cq = p * 256 + t;
            const int row = cq >> 3, bd = cq & 7;
            GLDS16(kbh + (size_t)(j0 + row) * DH + ((bd ^ (row & 7)) << 3), Ks + cq * 8);
        }
        // ---- V transpose (b32 pair writes into swizzled [d][j]) ----
        {
            const int j = 2 * jp, d0 = dgv * 8;
            bf16x8 va = *(const bf16x8*)(vbh + (size_t)(j0 + j)     * DH + d0);
            bf16x8 vb = *(const bf16x8*)(vbh + (size_t)(j0 + j + 1) * DH + d0);
#pragma unroll
            for (int c = 0; c < 8; ++c) {
                const int d = d0 + c;
                const int slot = d * 64 + (((j >> 3) ^ (d & 7)) << 3) + (j & 7);
                short2 pr; pr.x = va[c]; pr.y = vb[c];
                *(short2*)&Vt[slot] = pr;
            }
        }
        __syncthreads();

        // ---- C-init from padded c2p (no clamps; idx in [1,4095]) ----
        f32x4 st4[4];
        const int cbB = 2048 + i0 + iLoc - j0;      // idx = cbB - jl
#pragma unroll
        for (int jt = 0; jt < 4; ++jt) {
            const int base = cbB - jt*16 - q4*4;
            st4[jt][0] = c2pb[base];
            st4[jt][1] = c2pb[base - 1];
            st4[jt][2] = c2pb[base - 2];
            st4[jt][3] = c2pb[base - 3];
        }

        // ---- band prefetch direct from T-slab (XCD L2), clamped y ----
        short tband[16];
#pragma unroll
        for (int jt = 0; jt < 4; ++jt)
#pragma unroll
            for (int r = 0; r < 4; ++r) {
                const int jl = jt*16 + q4*4 + r;
                const int y  = min(max(Kc0 - jl - iLoc, 0), TAB - 1);
                tband[jt*4 + r] = Tb[(size_t)(j0 + jl) * 1024 + y];
            }

        // ---- swapped QK^T: mfma(K_frag, Q_frag) -> S^T ----
        __builtin_amdgcn_s_setprio(1);
#pragma unroll
        for (int jt = 0; jt < 4; ++jt) {
            bf16x8 a0 = fragS(Ks, jt*16 + l, q4);
            bf16x8 a1 = fragS(Ks, jt*16 + l, 4 + q4);
            st4[jt] = __builtin_amdgcn_mfma_f32_16x16x32_bf16(a0, aq0, st4[jt], 0, 0, 0);
            st4[jt] = __builtin_amdgcn_mfma_f32_16x16x32_bf16(a1, aq1, st4[jt], 0, 0, 0);
        }
        __builtin_amdgcn_s_setprio(0);

        // ---- exp2 (uniform path; bias from registers) ----
        float pv4[4][4];
#pragma unroll
        for (int jt = 0; jt < 4; ++jt)
#pragma unroll
            for (int r = 0; r < 4; ++r) {
                pv4[jt][r] = EXP2F(st4[jt][r] + b2f(tband[jt*4 + r]));
                lsum += pv4[jt][r];
            }

        // ---- pack + permlane16_swap: PV A-frags in registers ----
        unsigned P2[4][2];
#pragma unroll
        for (int t2 = 0; t2 < 4; ++t2) {
            asm("v_cvt_pk_bf16_f32 %0, %1, %2"
                : "=v"(P2[t2][0]) : "v"(pv4[t2][0]), "v"(pv4[t2][1]));
            asm("v_cvt_pk_bf16_f32 %0, %1, %2"
                : "=v"(P2[t2][1]) : "v"(pv4[t2][2]), "v"(pv4[t2][3]));
        }
#pragma unroll
        for (int m = 0; m < 2; ++m) {
            asm("v_permlane16_swap_b32 %0, %1" : "+v"(P2[0][m]), "+v"(P2[1][m]));
            asm("v_permlane16_swap_b32 %0, %1" : "+v"(P2[2][m]), "+v"(P2[3][m]));
        }
        union { unsigned u[4]; bf16x8 v8; } UA, UB;
        UA.u[0] = P2[0][0]; UA.u[1] = P2[0][1]; UA.u[2] = P2[1][0]; UA.u[3] = P2[1][1];
        UB.u[0] = P2[2][0]; UB.u[1] = P2[2][1]; UB.u[2] = P2[3][0]; UB.u[3] = P2[3][1];

        // ---- PV (A = in-register P frags, B = V frags with granule perm) ----
        __builtin_amdgcn_s_setprio(1);
#pragma unroll
        for (int dt = 0; dt < 4; ++dt) {
            bf16x8 b0 = fragS(Vt, dt*16 + l, pq);
            bf16x8 b1 = fragS(Vt, dt*16 + l, 4 + pq);
            O[dt] = __builtin_amdgcn_mfma_f32_16x16x32_bf16(UA.v8, b0, O[dt], 0, 0, 0);
            O[dt] = __builtin_amdgcn_mfma_f32_16x16x32_bf16(UB.v8, b1, O[dt], 0, 0, 0);
        }
        __builtin_amdgcn_s_setprio(0);
        __syncthreads();   // compute done before next stage overwrites Ks/Vt
    }

    // ---- final row-sum: reduce q4-groups, then pick per-output-row ----
    lsum += __shfl_xor(lsum, 16);
    lsum += __shfl_xor(lsum, 32);

    // ---- epilogue: normalize, write ao bf16 as [b][s][h][d] ----
#pragma unroll
    for (int r = 0; r < 4; ++r) {
        const float inv = 1.f / __shfl(lsum, q4*4 + r);
        const int i_g = i0 + w*16 + q4*4 + r;
        short* dst = ao + (((size_t)b_ * SEQ + i_g) * NH + h_) * DH + l;
#pragma unroll
        for (int dt = 0; dt < 4; ++dt)
            dst[dt*16] = f2b(O[dt][r] * inv);
    }
}

// ---------------------------------------------------------------------------
// Kernel 5: output projection out = ao @ Wc.T (A bf16 glds, B fp32->bf16)
// ---------------------------------------------------------------------------
__global__ __launch_bounds__(256) void out_mfma_kernel(
    const short* __restrict__ xb, const float* __restrict__ W, float* __restrict__ out)
{
    const int m0 = blockIdx.y * 128;
    const int n0 = blockIdx.x * 128;

    __shared__ short As[128 * 64];
    __shared__ short Bs[128 * 64];

    const int t  = threadIdx.x;
    const int w  = t >> 6;
    const int q4 = (t >> 4) & 3;
    const int l  = t & 15;
    const int wm = (w >> 1) * 64;
    const int wn = (w & 1) * 64;

    f32x4 acc[4][4];
#pragma unroll
    for (int mt = 0; mt < 4; ++mt)
#pragma unroll
        for (int nt = 0; nt < 4; ++nt) acc[mt][nt] = (f32x4){0.f,0.f,0.f,0.f};

    for (int k0 = 0; k0 < DIM; k0 += 64) {
        __syncthreads();
#pragma unroll
        for (int p = 0; p < 4; ++p) {
            const int cq = p * 256 + t;
            const int row = cq >> 3, bd = cq & 7;
            GLDS16(xb + (size_t)(m0 + row) * DIM + k0 + ((bd ^ (row & 7)) << 3), As + cq * 8);
        }
        {
            const int row = t >> 1, h = t & 1;
#pragma unroll
            for (int c = 0; c < 4; ++c) {
                const int gch = h * 4 + c;
                const float* src = W + (size_t)(n0 + row) * DIM + k0 + gch * 8;
                float4 f0 = *(const float4*)src;
                float4 f1 = *(const float4*)(src + 4);
                bf16x8 o = { f2b(f0.x), f2b(f0.y), f2b(f0.z), f2b(f0.w),
                             f2b(f1.x), f2b(f1.y), f2b(f1.z), f2b(f1.w) };
                *(bf16x8*)&Bs[row * 64 + ((gch ^ (row & 7)) << 3)] = o;
            }
        }
        __syncthreads();
#pragma unroll
        for (int kc = 0; kc < 2; ++kc) {
            bf16x8 af[4], bf[4];
#pragma unroll
            for (int mt = 0; mt < 4; ++mt) af[mt] = fragS(As, wm + mt*16 + l, kc*4 + q4);
#pragma unroll
            for (int nt = 0; nt < 4; ++nt) bf[nt] = fragS(Bs, wn + nt*16 + l, kc*4 + q4);
#pragma unroll
            for (int mt = 0; mt < 4; ++mt)
#pragma unroll
                for (int nt = 0; nt < 4; ++nt)
                    acc[mt][nt] = __builtin_amdgcn_mfma_f32_16x16x32_bf16(
                        af[mt], bf[nt], acc[mt][nt], 0, 0, 0);
        }
    }
#pragma unroll
    for (int mt = 0; mt < 4; ++mt)
#pragma unroll
        for (int r = 0; r < 4; ++r) {
            const int m = m0 + wm + mt*16 + q4*4 + r;
#pragma unroll
            for (int nt = 0; nt < 4; ++nt)
                out[(size_t)m * DIM + n0 + wn + nt*16 + l] = acc[mt][nt][r];
        }
}

// ---------------------------------------------------------------------------
extern "C" void kernel_launch(void* const* d_in, const int* in_sizes, int n_in,
                              void* d_out, int out_size, void* d_ws, size_t ws_size,
                              hipStream_t stream)
{
    const float* hs = (const float*)d_in[0];
    const float* Wq = (const float*)d_in[1];
    const float* bq = (const float*)d_in[2];
    const float* Wk = (const float*)d_in[3];
    const float* bk = (const float*)d_in[4];
    const float* Wv = (const float*)d_in[5];
    const float* bv = (const float*)d_in[6];
    const float* Wc = (const float*)d_in[7];
    const float* pt = (const float*)d_in[8];
    float* out = (float*)d_out;

    // workspace (shorts): [qb][kb][vb][aob][c2pP fp32 padded][ptb bf16][slab]
    // phase-1 overlay inside slab region: xb + Wq/Wk/Wv bf16.
    const size_t XE    = (size_t)BN * SEQ * DIM;     // 4,194,304
    const size_t WE    = (size_t)DIM * DIM;          // 1,048,576
    const size_t PE    = (size_t)TAB * DH;           // 65,536
    const size_t CPSH  = (size_t)BN * NH * C2PP * 2; // padded c2p in shorts
    const size_t SLAB1 = (size_t)SEQ * 1024;         // shorts per bh

    short* sw   = (short*)d_ws;
    short* qb   = sw;
    short* kb   = sw + XE;
    short* vb   = sw + 2 * XE;
    short* aob  = sw + 3 * XE;
    float* c2pP = (float*)(sw + 4 * XE);             // BN*NH*C2PP fp32
    short* ptb  = sw + 4 * XE + CPSH;                // pos_table bf16
    short* slab = sw + 4 * XE + CPSH + PE;
    short* xb   = slab;                  // overlay (phase 1 only)
    short* wqb  = slab + XE;
    short* wkb  = wqb + WE;
    short* wvb  = wkb + WE;

    const size_t fixed_sh = 4 * XE + CPSH + PE;
    const size_t avail_sh = (ws_size / 2 > fixed_sh) ? ws_size / 2 - fixed_sh : 0;
    const int G = (avail_sh >= 32 * SLAB1) ? 32 : ((avail_sh >= 16 * SLAB1) ? 16 : 8);

    f2b_multi_kernel<<<dim3((int)(XE/2048), 1, 5), 256, 0, stream>>>(
        hs, xb, (int)XE, Wq, wqb, Wk, wkb, Wv, wvb, (int)WE, pt, ptb, (int)PE);

    qkv_mfma_kernel<<<dim3(DIM/128, (BN*SEQ)/128, 3), 256, 0, stream>>>(
        xb, wqb, bq, wkb, bk, wvb, bv, qb, kb, vb);

    qsum_c2p_kernel<<<dim3(BN*NH), 256, 0, stream>>>(qb, pt, c2pP);

    for (int bh0 = 0; bh0 < BN*NH; bh0 += G) {
        tgemm_kernel<<<dim3(1024/128, SEQ/128, G), 256, 0, stream>>>(kb, ptb, slab, bh0);
        attn_kernel<<<dim3(SEQ/64, G), 256, 0, stream>>>(qb, kb, vb, c2pP, slab, aob, bh0);
    }

    out_mfma_kernel<<<dim3(DIM/128, (BN*SEQ)/128), 256, 0, stream>>>(aob, Wc, out);
}